// Round 2
// 370.169 us; speedup vs baseline: 1.2859x; 1.2859x over previous
//
#include <hip/hip_runtime.h>
#include <hip/hip_bf16.h>

#define NREF 131072
#define NALT 32768
#define BSEG 4096
#define D 128
#define F 512
#define H 256
#define EPS 1e-5f

typedef short short8 __attribute__((ext_vector_type(8)));
typedef float f32x4 __attribute__((ext_vector_type(4)));

__device__ __forceinline__ float selu_f(float z) {
    const float sc = 1.0507009873554805f;
    const float al = 1.6732632423543772f;
    return z > 0.f ? sc * z : sc * al * (__expf(z) - 1.f);
}

__device__ __forceinline__ short f2bf(float v) {
    __bf16 b = (__bf16)v;
    return __builtin_bit_cast(short, b);
}

// Pack fp32 KxN weight into bf16 MFMA B-fragment layout for 16x16x32:
// frag index ((nt*KT + kt)*64 + lane)*8 + j  <->  B[kt*32 + (lane>>4)*8 + j][nt*16 + (lane&15)]
__global__ void pack_w(const float* __restrict__ w, __bf16* __restrict__ wp, int KT, int N) {
    int idx = blockIdx.x * 256 + threadIdx.x;
    int j = idx & 7;
    int l = (idx >> 3) & 63;
    int t = idx >> 9;
    int kt = t % KT;
    int nt = t / KT;
    int k = kt * 32 + ((l >> 4) << 3) + j;
    int n = (nt << 4) + (l & 15);
    wp[idx] = (__bf16)w[k * N + n];
}

// Pass 1: LN1 -> half GEMM1 (z2 columns) -> SELU -> LN2 -> segment sums (atomics)
__global__ __launch_bounds__(256, 3)
void pass1_kernel(const float* __restrict__ x, const int* __restrict__ seg,
                  const __bf16* __restrict__ w1p, const float* __restrict__ b1,
                  const float* __restrict__ n1w, const float* __restrict__ n1b,
                  const float* __restrict__ n2w, const float* __restrict__ n2b,
                  float* __restrict__ seg_sum, float* __restrict__ seg_cnt) {
    __shared__ __align__(16) __bf16 ys[32 * 128];   // XOR-swizzled: idx = r*128 + (col ^ ((r&7)<<3))
    __shared__ float z2s[32][257];
    __shared__ float n2w_s[H], n2b_s[H], b1h_s[H];
    __shared__ int seg_s[32];

    const int tid = threadIdx.x;
    const int lane = tid & 63;
    const int wv = tid >> 6;
    const size_t row0 = (size_t)blockIdx.x * 32;

    // Preload ALL GEMM1 b-frags (wave wv owns nt_g = 16+wv*4 .. +3) — issued first,
    // latency hides under x-load + LN1.
    short8 bb[4][4];
    #pragma unroll
    for (int p = 0; p < 4; ++p)
        #pragma unroll
        for (int kt = 0; kt < 4; ++kt)
            bb[p][kt] = *reinterpret_cast<const short8*>(
                w1p + ((size_t)((16 + wv * 4 + p) * 4 + kt) * 64 + lane) * 8);

    const int r = tid >> 3, g = tid & 7;
    float xr[16];
    #pragma unroll
    for (int i = 0; i < 4; ++i) {
        float4 t = *reinterpret_cast<const float4*>(x + (row0 + r) * D + g * 16 + i * 4);
        xr[i * 4 + 0] = t.x; xr[i * 4 + 1] = t.y; xr[i * 4 + 2] = t.z; xr[i * 4 + 3] = t.w;
    }
    // LN1 weights straight to registers (NO LDS: avoids pre-barrier cross-wave race)
    float w1r[16], c1r[16];
    #pragma unroll
    for (int i = 0; i < 4; ++i) {
        float4 t = *reinterpret_cast<const float4*>(n1w + g * 16 + i * 4);
        w1r[i * 4 + 0] = t.x; w1r[i * 4 + 1] = t.y; w1r[i * 4 + 2] = t.z; w1r[i * 4 + 3] = t.w;
        float4 u = *reinterpret_cast<const float4*>(n1b + g * 16 + i * 4);
        c1r[i * 4 + 0] = u.x; c1r[i * 4 + 1] = u.y; c1r[i * 4 + 2] = u.z; c1r[i * 4 + 3] = u.w;
    }

    n2w_s[tid] = n2w[tid]; n2b_s[tid] = n2b[tid];
    b1h_s[tid] = b1[H + tid];
    if (tid < 32) seg_s[tid] = seg[row0 + tid];

    { // LN1 fully in registers (8 threads/row)
        float s = 0.f, ss = 0.f;
        #pragma unroll
        for (int i = 0; i < 16; ++i) { s += xr[i]; ss += xr[i] * xr[i]; }
        s += __shfl_xor(s, 1); ss += __shfl_xor(ss, 1);
        s += __shfl_xor(s, 2); ss += __shfl_xor(ss, 2);
        s += __shfl_xor(s, 4); ss += __shfl_xor(ss, 4);
        float mean = s * (1.f / 128.f);
        float var = ss * (1.f / 128.f) - mean * mean;
        float rsv = rsqrtf(var + EPS);
        const int swr = (r & 7) << 3;
        #pragma unroll
        for (int h = 0; h < 2; ++h) {
            short8 pk;
            #pragma unroll
            for (int j = 0; j < 8; ++j) {
                pk[j] = f2bf((xr[h * 8 + j] - mean) * rsv * w1r[h * 8 + j] + c1r[h * 8 + j]);
            }
            *reinterpret_cast<short8*>(&ys[r * 128 + ((g * 16 + h * 8) ^ swr)]) = pk;
        }
    }
    __syncthreads();

    { // half GEMM1: out 32x256 (z2 cols 256..511), wave wv: 4 nt x 2 mt x 4 kt
        const int m0 = lane & 15;
        const int swm = (m0 & 7) << 3;
        const int ccol = (lane >> 4) << 3;
        short8 a0[4], a1[4];
        #pragma unroll
        for (int kt = 0; kt < 4; ++kt) {
            a0[kt] = *reinterpret_cast<const short8*>(&ys[m0 * 128 + ((kt * 32 + ccol) ^ swm)]);
            a1[kt] = *reinterpret_cast<const short8*>(&ys[(m0 + 16) * 128 + ((kt * 32 + ccol) ^ swm)]);
        }
        #pragma unroll
        for (int nt = 0; nt < 4; ++nt) {
            f32x4 acc0 = {0.f, 0.f, 0.f, 0.f};
            f32x4 acc1 = {0.f, 0.f, 0.f, 0.f};
            #pragma unroll
            for (int kt = 0; kt < 4; ++kt) {
                acc0 = __builtin_amdgcn_mfma_f32_16x16x32_bf16(a0[kt], bb[nt][kt], acc0, 0, 0, 0);
                acc1 = __builtin_amdgcn_mfma_f32_16x16x32_bf16(a1[kt], bb[nt][kt], acc1, 0, 0, 0);
            }
            int cz = (wv * 4 + nt) * 16 + m0;   // 0..255 within z2
            float bbias = b1h_s[cz];
            #pragma unroll
            for (int reg = 0; reg < 4; ++reg) {
                int r0 = ((lane >> 4) << 2) + reg;
                z2s[r0][cz] = selu_f(acc0[reg] + bbias);
                z2s[r0 + 16][cz] = selu_f(acc1[reg] + bbias);
            }
        }
    }
    __syncthreads();

    { // LN2 in place (stride-4 column groups: bank-conflict-light)
        float s2 = 0.f, q2 = 0.f;
        float z2c[32];
        #pragma unroll
        for (int c = 0; c < 32; ++c) {
            int col = g * 4 + (c & 3) + ((c >> 2) << 5);
            float v = z2s[r][col];
            z2c[c] = v; s2 += v; q2 += v * v;
        }
        s2 += __shfl_xor(s2, 1); q2 += __shfl_xor(q2, 1);
        s2 += __shfl_xor(s2, 2); q2 += __shfl_xor(q2, 2);
        s2 += __shfl_xor(s2, 4); q2 += __shfl_xor(q2, 4);
        float mean2 = s2 * (1.f / 256.f);
        float var2 = q2 * (1.f / 256.f) - mean2 * mean2;
        float rs2 = rsqrtf(var2 + EPS);
        #pragma unroll
        for (int c = 0; c < 32; ++c) {
            int col = g * 4 + (c & 3) + ((c >> 2) << 5);
            z2s[r][col] = (z2c[c] - mean2) * rs2 * n2w_s[col] + n2b_s[col];
        }
    }
    __syncthreads();

    { // segment accumulate: thread = column, run-length compress (segments sorted)
        int c = tid;
        int s_cur = seg_s[0];
        float run = 0.f;
        for (int rr = 0; rr < 32; ++rr) {
            int sg = seg_s[rr];
            if (sg != s_cur) {
                atomicAdd(&seg_sum[(size_t)s_cur * H + c], run);
                run = 0.f; s_cur = sg;
            }
            run += z2s[rr][c];
        }
        atomicAdd(&seg_sum[(size_t)s_cur * H + c], run);
        if (tid == 0) {
            int sc = seg_s[0]; float rl = 0.f;
            for (int rr = 0; rr < 32; ++rr) {
                if (seg_s[rr] != sc) { atomicAdd(&seg_cnt[sc], rl); rl = 0.f; sc = seg_s[rr]; }
                rl += 1.f;
            }
            atomicAdd(&seg_cnt[sc], rl);
        }
    }
}

// Per-segment gate offsets: G_ref = beta_ref*mf_ref ; G_alt = beta_alt*mf_alt + gamma*mf_ref
__global__ void mf_kernel(const float* __restrict__ sum_r, const float* __restrict__ cnt_r,
                          const float* __restrict__ sum_a, const float* __restrict__ cnt_a,
                          const float* __restrict__ regz, const float* __restrict__ reg_w_pre,
                          const float* __restrict__ beta_ref, const float* __restrict__ beta_alt,
                          const float* __restrict__ gamma,
                          float* __restrict__ G_ref, float* __restrict__ G_alt) {
    int s = blockIdx.x, c = threadIdx.x;
    size_t i = (size_t)s * H + c;
    float rw = __expf(reg_w_pre[0]) + 0.25f;
    float mfr = (sum_r[i] + rw * regz[c]) / (cnt_r[s] + rw);
    float mfa = sum_a[i] / fmaxf(cnt_a[s], 1.f);
    G_ref[i] = beta_ref[0] * mfr;
    G_alt[i] = beta_alt[0] * mfa + gamma[0] * mfr;
}

// Pass 2: LN1 -> GEMM1 -> SELU -> LN2 -> gate -> GEMM2 -> +x +b2 -> out
__global__ __launch_bounds__(256, 3)
void pass2_kernel(const float* __restrict__ x, const int* __restrict__ seg,
                  const __bf16* __restrict__ w1p, const float* __restrict__ b1,
                  const __bf16* __restrict__ w2p, const float* __restrict__ b2,
                  const float* __restrict__ n1w, const float* __restrict__ n1b,
                  const float* __restrict__ n2w, const float* __restrict__ n2b,
                  const float* __restrict__ alpha_p, const float* __restrict__ G,
                  float* __restrict__ out) {
    __shared__ __align__(16) __bf16 ys[32 * 128];   // XOR-swizzled
    __shared__ __align__(16) __bf16 zs[32 * 512];   // XOR-swizzled: idx = r*512 + (col ^ ((r&7)<<3))
    __shared__ float n2w_s[H], n2b_s[H], b1_s[F], b2_s[D];
    __shared__ int seg_s[32];
    __shared__ float alpha_s;

    const int tid = threadIdx.x;
    const int lane = tid & 63;
    const int wv = tid >> 6;
    const size_t row0 = (size_t)blockIdx.x * 32;

    // GEMM1 b-frag ring (wave wv owns nt_g = wv*8 .. +7): preload first 4 nt now.
    short8 bb[4][4];
    #pragma unroll
    for (int p = 0; p < 4; ++p)
        #pragma unroll
        for (int kt = 0; kt < 4; ++kt)
            bb[p][kt] = *reinterpret_cast<const short8*>(
                w1p + ((size_t)((wv * 8 + p) * 4 + kt) * 64 + lane) * 8);

    const int r = tid >> 3, g = tid & 7;
    float xr[16];
    #pragma unroll
    for (int i = 0; i < 4; ++i) {
        float4 t = *reinterpret_cast<const float4*>(x + (row0 + r) * D + g * 16 + i * 4);
        xr[i * 4 + 0] = t.x; xr[i * 4 + 1] = t.y; xr[i * 4 + 2] = t.z; xr[i * 4 + 3] = t.w;
    }
    // LN1 weights straight to registers (NO LDS: avoids pre-barrier cross-wave race)
    float w1r[16], c1r[16];
    #pragma unroll
    for (int i = 0; i < 4; ++i) {
        float4 t = *reinterpret_cast<const float4*>(n1w + g * 16 + i * 4);
        w1r[i * 4 + 0] = t.x; w1r[i * 4 + 1] = t.y; w1r[i * 4 + 2] = t.z; w1r[i * 4 + 3] = t.w;
        float4 u = *reinterpret_cast<const float4*>(n1b + g * 16 + i * 4);
        c1r[i * 4 + 0] = u.x; c1r[i * 4 + 1] = u.y; c1r[i * 4 + 2] = u.z; c1r[i * 4 + 3] = u.w;
    }

    if (tid < D) b2_s[tid] = b2[tid];
    n2w_s[tid] = n2w[tid]; n2b_s[tid] = n2b[tid];
    b1_s[tid] = b1[tid]; b1_s[tid + 256] = b1[tid + 256];
    if (tid < 32) seg_s[tid] = seg[row0 + tid];
    if (tid == 0) alpha_s = alpha_p[0];

    { // LN1 fully in registers
        float s = 0.f, ss = 0.f;
        #pragma unroll
        for (int i = 0; i < 16; ++i) { s += xr[i]; ss += xr[i] * xr[i]; }
        s += __shfl_xor(s, 1); ss += __shfl_xor(ss, 1);
        s += __shfl_xor(s, 2); ss += __shfl_xor(ss, 2);
        s += __shfl_xor(s, 4); ss += __shfl_xor(ss, 4);
        float mean = s * (1.f / 128.f);
        float var = ss * (1.f / 128.f) - mean * mean;
        float rsv = rsqrtf(var + EPS);
        const int swr = (r & 7) << 3;
        #pragma unroll
        for (int h = 0; h < 2; ++h) {
            short8 pk;
            #pragma unroll
            for (int j = 0; j < 8; ++j) {
                pk[j] = f2bf((xr[h * 8 + j] - mean) * rsv * w1r[h * 8 + j] + c1r[h * 8 + j]);
            }
            *reinterpret_cast<short8*>(&ys[r * 128 + ((g * 16 + h * 8) ^ swr)]) = pk;
        }
    }
    __syncthreads();

    { // GEMM1 full 32x512: wave wv: 8 nt x 2 mt x 4 kt, 4-deep b-frag ring
        const int m0 = lane & 15;
        const int swm = (m0 & 7) << 3;
        const int ccol = (lane >> 4) << 3;
        short8 a0[4], a1[4];
        #pragma unroll
        for (int kt = 0; kt < 4; ++kt) {
            a0[kt] = *reinterpret_cast<const short8*>(&ys[m0 * 128 + ((kt * 32 + ccol) ^ swm)]);
            a1[kt] = *reinterpret_cast<const short8*>(&ys[(m0 + 16) * 128 + ((kt * 32 + ccol) ^ swm)]);
        }
        #pragma unroll
        for (int nt = 0; nt < 8; ++nt) {
            f32x4 acc0 = {0.f, 0.f, 0.f, 0.f};
            f32x4 acc1 = {0.f, 0.f, 0.f, 0.f};
            #pragma unroll
            for (int kt = 0; kt < 4; ++kt) {
                acc0 = __builtin_amdgcn_mfma_f32_16x16x32_bf16(a0[kt], bb[nt & 3][kt], acc0, 0, 0, 0);
                acc1 = __builtin_amdgcn_mfma_f32_16x16x32_bf16(a1[kt], bb[nt & 3][kt], acc1, 0, 0, 0);
            }
            if (nt < 4) {   // prefetch nt+4 into the slot just consumed
                #pragma unroll
                for (int kt = 0; kt < 4; ++kt)
                    bb[nt & 3][kt] = *reinterpret_cast<const short8*>(
                        w1p + ((size_t)((wv * 8 + nt + 4) * 4 + kt) * 64 + lane) * 8);
            }
            int colg = (wv * 8 + nt) * 16 + m0;
            float bbias = b1_s[colg];
            #pragma unroll
            for (int reg = 0; reg < 4; ++reg) {
                int r0 = ((lane >> 4) << 2) + reg;
                zs[r0 * 512 + (colg ^ ((r0 & 7) << 3))] = (__bf16)selu_f(acc0[reg] + bbias);
                zs[(r0 + 16) * 512 + (colg ^ ((r0 & 7) << 3))] = (__bf16)selu_f(acc1[reg] + bbias);
            }
        }
    }

    // Issue GEMM2 weight frags + residual-x reads NOW — latency hides under LN2.
    short8 b2f[2][8];
    #pragma unroll
    for (int p = 0; p < 2; ++p)
        #pragma unroll
        for (int kt = 0; kt < 8; ++kt)
            b2f[p][kt] = *reinterpret_cast<const short8*>(
                w2p + ((size_t)((wv * 2 + p) * 8 + kt) * 64 + lane) * 8);
    float xres[16];
    #pragma unroll
    for (int p = 0; p < 2; ++p) {
        int col = (wv * 2 + p) * 16 + (lane & 15);
        #pragma unroll
        for (int reg = 0; reg < 4; ++reg) {
            int r0 = ((lane >> 4) << 2) + reg;
            xres[p * 8 + reg]     = x[(row0 + r0) * D + col];
            xres[p * 8 + 4 + reg] = x[(row0 + r0 + 16) * D + col];
        }
    }
    __syncthreads();

    { // LN2 on z2 (cols 256..511) + gate, write A2 = z1*gate over z1 cols
        const int swr2 = (r & 7) << 3;
        float s2 = 0.f, q2 = 0.f;
        float z2c[32];
        #pragma unroll
        for (int c = 0; c < 32; ++c) {
            int col = g * 4 + (c & 3) + ((c >> 2) << 5);
            float v = (float)zs[r * 512 + ((256 + col) ^ swr2)];
            z2c[c] = v; s2 += v; q2 += v * v;
        }
        s2 += __shfl_xor(s2, 1); q2 += __shfl_xor(q2, 1);
        s2 += __shfl_xor(s2, 2); q2 += __shfl_xor(q2, 2);
        s2 += __shfl_xor(s2, 4); q2 += __shfl_xor(q2, 4);
        float mean2 = s2 * (1.f / 256.f);
        float var2 = q2 * (1.f / 256.f) - mean2 * mean2;
        float rs2 = rsqrtf(var2 + EPS);
        const float* Grow = G + (size_t)seg_s[r] * H;
        float al = alpha_s;
        #pragma unroll
        for (int c = 0; c < 32; ++c) {
            int col = g * 4 + (c & 3) + ((c >> 2) << 5);
            float z2n = (z2c[c] - mean2) * rs2 * n2w_s[col] + n2b_s[col];
            float gate = z2n * al + 1.f + Grow[col];
            int idx = r * 512 + (col ^ swr2);
            zs[idx] = (__bf16)((float)zs[idx] * gate);
        }
    }
    __syncthreads();

    { // GEMM2: (32x256)@(256x128), direct store out = acc + b2 + x
        const int m0 = lane & 15;
        const int swm = (m0 & 7) << 3;
        const int ccol = (lane >> 4) << 3;
        f32x4 zero = {0.f, 0.f, 0.f, 0.f};
        f32x4 acc[2][2] = {{zero, zero}, {zero, zero}};
        #pragma unroll
        for (int kt = 0; kt < 8; ++kt) {
            short8 a0 = *reinterpret_cast<const short8*>(&zs[m0 * 512 + ((kt * 32 + ccol) ^ swm)]);
            short8 a1 = *reinterpret_cast<const short8*>(&zs[(m0 + 16) * 512 + ((kt * 32 + ccol) ^ swm)]);
            #pragma unroll
            for (int p = 0; p < 2; ++p) {
                acc[p][0] = __builtin_amdgcn_mfma_f32_16x16x32_bf16(a0, b2f[p][kt], acc[p][0], 0, 0, 0);
                acc[p][1] = __builtin_amdgcn_mfma_f32_16x16x32_bf16(a1, b2f[p][kt], acc[p][1], 0, 0, 0);
            }
        }
        #pragma unroll
        for (int p = 0; p < 2; ++p) {
            int col = (wv * 2 + p) * 16 + m0;
            float b2v = b2_s[col];
            #pragma unroll
            for (int reg = 0; reg < 4; ++reg) {
                int r0 = ((lane >> 4) << 2) + reg;
                out[(row0 + r0) * D + col]      = acc[p][0][reg] + b2v + xres[p * 8 + reg];
                out[(row0 + r0 + 16) * D + col] = acc[p][1][reg] + b2v + xres[p * 8 + 4 + reg];
            }
        }
    }
}

extern "C" void kernel_launch(void* const* d_in, const int* in_sizes, int n_in,
                              void* d_out, int out_size, void* d_ws, size_t ws_size,
                              hipStream_t stream) {
    const float* ref_flat = (const float*)d_in[0];
    const float* alt_flat = (const float*)d_in[1];
    const int*   ref_seg  = (const int*)d_in[2];
    const int*   alt_seg  = (const int*)d_in[3];
    const float* norm1_w  = (const float*)d_in[4];
    const float* norm1_b  = (const float*)d_in[5];
    const float* w1_ref   = (const float*)d_in[6];
    const float* b1_ref   = (const float*)d_in[7];
    const float* w1_alt   = (const float*)d_in[8];
    const float* b1_alt   = (const float*)d_in[9];
    const float* norm2_w  = (const float*)d_in[10];
    const float* norm2_b  = (const float*)d_in[11];
    const float* alpha_ref = (const float*)d_in[12];
    const float* alpha_alt = (const float*)d_in[13];
    const float* beta_ref  = (const float*)d_in[14];
    const float* beta_alt  = (const float*)d_in[15];
    const float* gamma     = (const float*)d_in[16];
    const float* ref_regularizer = (const float*)d_in[17];
    const float* reg_w_pre = (const float*)d_in[18];
    const float* w2_ref   = (const float*)d_in[19];
    const float* b2_ref   = (const float*)d_in[20];
    const float* w2_alt   = (const float*)d_in[21];
    const float* b2_alt   = (const float*)d_in[22];

    char* ws = (char*)d_ws;
    float* sum_r = (float*)(ws);                      // 4 MB
    float* sum_a = (float*)(ws + 4194304);            // 4 MB
    float* cnt_r = (float*)(ws + 8388608);            // 16 KB
    float* cnt_a = (float*)(ws + 8404992);            // 16 KB
    float* G_ref = (float*)(ws + 8421376);            // 4 MB
    float* G_alt = (float*)(ws + 12615680);           // 4 MB
    __bf16* w1p_r = (__bf16*)(ws + 16809984);         // 128 KB
    __bf16* w1p_a = (__bf16*)(ws + 16941056);         // 128 KB
    __bf16* w2p_r = (__bf16*)(ws + 17072128);         // 64 KB
    __bf16* w2p_a = (__bf16*)(ws + 17137664);         // 64 KB

    hipMemsetAsync(d_ws, 0, 8421376, stream);  // zero sums + counts (atomic targets)

    pack_w<<<256, 256, 0, stream>>>(w1_ref, w1p_r, 4, F);
    pack_w<<<256, 256, 0, stream>>>(w1_alt, w1p_a, 4, F);
    pack_w<<<128, 256, 0, stream>>>(w2_ref, w2p_r, 8, D);
    pack_w<<<128, 256, 0, stream>>>(w2_alt, w2p_a, 8, D);

    pass1_kernel<<<NREF/32, 256, 0, stream>>>(ref_flat, ref_seg, w1p_r, b1_ref,
                                              norm1_w, norm1_b, norm2_w, norm2_b, sum_r, cnt_r);
    pass1_kernel<<<NALT/32, 256, 0, stream>>>(alt_flat, alt_seg, w1p_a, b1_alt,
                                              norm1_w, norm1_b, norm2_w, norm2_b, sum_a, cnt_a);

    mf_kernel<<<BSEG, 256, 0, stream>>>(sum_r, cnt_r, sum_a, cnt_a, ref_regularizer, reg_w_pre,
                                        beta_ref, beta_alt, gamma, G_ref, G_alt);

    pass2_kernel<<<NREF/32, 256, 0, stream>>>(ref_flat, ref_seg, w1p_r, b1_ref, w2p_r, b2_ref,
                                              norm1_w, norm1_b, norm2_w, norm2_b,
                                              alpha_ref, G_ref, (float*)d_out);
    pass2_kernel<<<NALT/32, 256, 0, stream>>>(alt_flat, alt_seg, w1p_a, b1_alt, w2p_a, b2_alt,
                                              norm1_w, norm1_b, norm2_w, norm2_b,
                                              alpha_alt, G_alt, (float*)d_out + (size_t)NREF * D);
}

// Round 3
// 324.350 us; speedup vs baseline: 1.4675x; 1.1413x over previous
//
#include <hip/hip_runtime.h>
#include <hip/hip_bf16.h>

#define NREF 131072
#define NALT 32768
#define BSEG 4096
#define D 128
#define F 512
#define H 256
#define EPS 1e-5f

typedef short short8 __attribute__((ext_vector_type(8)));
typedef float f32x4 __attribute__((ext_vector_type(4)));

__device__ __forceinline__ float selu_f(float z) {
    const float sc = 1.0507009873554805f;
    const float al = 1.6732632423543772f;
    return z > 0.f ? sc * z : sc * al * (__expf(z) - 1.f);
}

__device__ __forceinline__ short f2bf(float v) {
    __bf16 b = (__bf16)v;
    return __builtin_bit_cast(short, b);
}

__device__ __forceinline__ float bf2f(short s) {
    return (float)__builtin_bit_cast(__bf16, s);
}

// Pack fp32 KxN weight into bf16 MFMA B-fragment layout for 16x16x32:
// frag index ((nt*KT + kt)*64 + lane)*8 + j  <->  B[kt*32 + (lane>>4)*8 + j][nt*16 + (lane&15)]
__global__ void pack_w(const float* __restrict__ w, __bf16* __restrict__ wp, int KT, int N) {
    int idx = blockIdx.x * 256 + threadIdx.x;
    int j = idx & 7;
    int l = (idx >> 3) & 63;
    int t = idx >> 9;
    int kt = t % KT;
    int nt = t / KT;
    int k = kt * 32 + ((l >> 4) << 3) + j;
    int n = (nt << 4) + (l & 15);
    wp[idx] = (__bf16)w[k * N + n];
}

// Pass 1: LN1 -> half GEMM1 (z2 cols) -> SELU -> LN2 -> seg sums + z2n store (bf16)
__global__ __launch_bounds__(256, 4)
void pass1_kernel(const float* __restrict__ x, const int* __restrict__ seg,
                  const __bf16* __restrict__ w1p, const float* __restrict__ b1,
                  const float* __restrict__ n1w, const float* __restrict__ n1b,
                  const float* __restrict__ n2w, const float* __restrict__ n2b,
                  float* __restrict__ seg_sum, float* __restrict__ seg_cnt,
                  __bf16* __restrict__ z2n_out) {
    __shared__ __align__(16) __bf16 ys[32 * 128];    // XOR-swz: idx = r*128 + (col ^ ((r&7)<<3))
    __shared__ __align__(16) __bf16 z2s[32 * 256];   // XOR-swz: idx = r*256 + (col ^ ((r&7)<<3))
    __shared__ float n2w_s[H], n2b_s[H];
    __shared__ int seg_s[32];

    const int tid = threadIdx.x;
    const int lane = tid & 63;
    const int wv = tid >> 6;
    const int q = lane >> 4, m0 = lane & 15;
    const size_t row0 = (size_t)blockIdx.x * 32;

    // 2-deep b-frag ring (wave wv owns nt_g = 16+wv*4 .. +3)
    short8 bb[2][4];
    #pragma unroll
    for (int p = 0; p < 2; ++p)
        #pragma unroll
        for (int kt = 0; kt < 4; ++kt)
            bb[p][kt] = *reinterpret_cast<const short8*>(
                w1p + ((size_t)((16 + wv * 4 + p) * 4 + kt) * 64 + lane) * 8);
    float b1v[4];
    #pragma unroll
    for (int nt = 0; nt < 4; ++nt) b1v[nt] = b1[256 + (wv * 4 + nt) * 16 + m0];

    const int r = tid >> 3, g = tid & 7;
    float xr[16];
    #pragma unroll
    for (int i = 0; i < 4; ++i) {
        float4 t = *reinterpret_cast<const float4*>(x + (row0 + r) * D + g * 16 + i * 4);
        xr[i * 4 + 0] = t.x; xr[i * 4 + 1] = t.y; xr[i * 4 + 2] = t.z; xr[i * 4 + 3] = t.w;
    }
    float w1r[16], c1r[16];   // LN1 weights in regs (no LDS -> no pre-barrier race)
    #pragma unroll
    for (int i = 0; i < 4; ++i) {
        float4 t = *reinterpret_cast<const float4*>(n1w + g * 16 + i * 4);
        w1r[i * 4 + 0] = t.x; w1r[i * 4 + 1] = t.y; w1r[i * 4 + 2] = t.z; w1r[i * 4 + 3] = t.w;
        float4 u = *reinterpret_cast<const float4*>(n1b + g * 16 + i * 4);
        c1r[i * 4 + 0] = u.x; c1r[i * 4 + 1] = u.y; c1r[i * 4 + 2] = u.z; c1r[i * 4 + 3] = u.w;
    }

    n2w_s[tid] = n2w[tid]; n2b_s[tid] = n2b[tid];
    if (tid < 32) seg_s[tid] = seg[row0 + tid];

    { // LN1 fully in registers (8 threads/row)
        float s = 0.f, ss = 0.f;
        #pragma unroll
        for (int i = 0; i < 16; ++i) { s += xr[i]; ss += xr[i] * xr[i]; }
        s += __shfl_xor(s, 1); ss += __shfl_xor(ss, 1);
        s += __shfl_xor(s, 2); ss += __shfl_xor(ss, 2);
        s += __shfl_xor(s, 4); ss += __shfl_xor(ss, 4);
        float mean = s * (1.f / 128.f);
        float var = ss * (1.f / 128.f) - mean * mean;
        float rsv = rsqrtf(var + EPS);
        const int swr = (r & 7) << 3;
        #pragma unroll
        for (int h = 0; h < 2; ++h) {
            short8 pk;
            #pragma unroll
            for (int j = 0; j < 8; ++j)
                pk[j] = f2bf((xr[h * 8 + j] - mean) * rsv * w1r[h * 8 + j] + c1r[h * 8 + j]);
            *reinterpret_cast<short8*>(&ys[r * 128 + ((g * 16 + h * 8) ^ swr)]) = pk;
        }
    }
    __syncthreads();

    { // half GEMM1 (z2 cols), wave wv: 4 nt x 2 mt x 4 kt
        const int swm = (m0 & 7) << 3;
        const int ccol = q << 3;
        short8 a0[4], a1[4];
        #pragma unroll
        for (int kt = 0; kt < 4; ++kt) {
            a0[kt] = *reinterpret_cast<const short8*>(&ys[m0 * 128 + ((kt * 32 + ccol) ^ swm)]);
            a1[kt] = *reinterpret_cast<const short8*>(&ys[(m0 + 16) * 128 + ((kt * 32 + ccol) ^ swm)]);
        }
        #pragma unroll
        for (int nt = 0; nt < 4; ++nt) {
            f32x4 acc0 = {0.f, 0.f, 0.f, 0.f};
            f32x4 acc1 = {0.f, 0.f, 0.f, 0.f};
            #pragma unroll
            for (int kt = 0; kt < 4; ++kt) {
                acc0 = __builtin_amdgcn_mfma_f32_16x16x32_bf16(a0[kt], bb[nt & 1][kt], acc0, 0, 0, 0);
                acc1 = __builtin_amdgcn_mfma_f32_16x16x32_bf16(a1[kt], bb[nt & 1][kt], acc1, 0, 0, 0);
            }
            if (nt < 2) {
                #pragma unroll
                for (int kt = 0; kt < 4; ++kt)
                    bb[nt & 1][kt] = *reinterpret_cast<const short8*>(
                        w1p + ((size_t)((16 + wv * 4 + nt + 2) * 4 + kt) * 64 + lane) * 8);
            }
            int cz = (wv * 4 + nt) * 16 + m0;   // 0..255 within z2
            #pragma unroll
            for (int reg = 0; reg < 4; ++reg) {
                int r0 = (q << 2) + reg;
                int r1 = r0 + 16;
                z2s[r0 * 256 + (cz ^ ((r0 & 7) << 3))] = (__bf16)selu_f(acc0[reg] + b1v[nt]);
                z2s[r1 * 256 + (cz ^ ((r1 & 7) << 3))] = (__bf16)selu_f(acc1[reg] + b1v[nt]);
            }
        }
    }
    __syncthreads();

    { // LN2 (thread = row, vectorized short8) + bf16 z2n store to global
        const int swr = (r & 7) << 3;
        float vb[32];
        float s2 = 0.f, q2 = 0.f;
        #pragma unroll
        for (int i = 0; i < 4; ++i) {
            short8 v = *reinterpret_cast<const short8*>(&z2s[r * 256 + ((g * 32 + i * 8) ^ swr)]);
            #pragma unroll
            for (int j = 0; j < 8; ++j) {
                float f = bf2f(v[j]);
                vb[i * 8 + j] = f; s2 += f; q2 += f * f;
            }
        }
        s2 += __shfl_xor(s2, 1); q2 += __shfl_xor(q2, 1);
        s2 += __shfl_xor(s2, 2); q2 += __shfl_xor(q2, 2);
        s2 += __shfl_xor(s2, 4); q2 += __shfl_xor(q2, 4);
        float mean2 = s2 * (1.f / 256.f);
        float var2 = q2 * (1.f / 256.f) - mean2 * mean2;
        float rs2 = rsqrtf(var2 + EPS);
        #pragma unroll
        for (int i = 0; i < 4; ++i) {
            short8 o;
            #pragma unroll
            for (int j = 0; j < 8; ++j) {
                int col = g * 32 + i * 8 + j;
                o[j] = f2bf((vb[i * 8 + j] - mean2) * rs2 * n2w_s[col] + n2b_s[col]);
            }
            *reinterpret_cast<short8*>(&z2s[r * 256 + ((g * 32 + i * 8) ^ swr)]) = o;
            *reinterpret_cast<short8*>(z2n_out + (row0 + r) * H + g * 32 + i * 8) = o;
        }
    }
    __syncthreads();

    { // segment accumulate: thread = column, run-length compress (segments sorted)
        int c = tid;
        int s_cur = seg_s[0];
        float run = 0.f;
        for (int rr = 0; rr < 32; ++rr) {
            int sg = seg_s[rr];
            if (sg != s_cur) {
                atomicAdd(&seg_sum[(size_t)s_cur * H + c], run);
                run = 0.f; s_cur = sg;
            }
            run += (float)z2s[rr * 256 + (c ^ ((rr & 7) << 3))];
        }
        atomicAdd(&seg_sum[(size_t)s_cur * H + c], run);
        if (tid == 0) {
            int sc = seg_s[0]; float rl = 0.f;
            for (int rr = 0; rr < 32; ++rr) {
                if (seg_s[rr] != sc) { atomicAdd(&seg_cnt[sc], rl); rl = 0.f; sc = seg_s[rr]; }
                rl += 1.f;
            }
            atomicAdd(&seg_cnt[sc], rl);
        }
    }
}

// G_ref = beta_ref * mf_ref
__global__ void mf_ref_kernel(const float* __restrict__ sum_r, const float* __restrict__ cnt_r,
                              const float* __restrict__ regz, const float* __restrict__ reg_w_pre,
                              const float* __restrict__ beta_ref, float* __restrict__ G_ref) {
    int s = blockIdx.x, c = threadIdx.x;
    size_t i = (size_t)s * H + c;
    float rw = __expf(reg_w_pre[0]) + 0.25f;
    float mfr = (sum_r[i] + rw * regz[c]) / (cnt_r[s] + rw);
    G_ref[i] = beta_ref[0] * mfr;
}

// G_alt = beta_alt * mf_alt + gamma * mf_ref
__global__ void mf_alt_kernel(const float* __restrict__ sum_r, const float* __restrict__ cnt_r,
                              const float* __restrict__ sum_a, const float* __restrict__ cnt_a,
                              const float* __restrict__ regz, const float* __restrict__ reg_w_pre,
                              const float* __restrict__ beta_alt, const float* __restrict__ gamma,
                              float* __restrict__ G_alt) {
    int s = blockIdx.x, c = threadIdx.x;
    size_t i = (size_t)s * H + c;
    float rw = __expf(reg_w_pre[0]) + 0.25f;
    float mfr = (sum_r[i] + rw * regz[c]) / (cnt_r[s] + rw);
    float mfa = sum_a[i] / fmaxf(cnt_a[s], 1.f);
    G_alt[i] = beta_alt[0] * mfa + gamma[0] * mfr;
}

// Pass 2: LN1 -> half GEMM1 (z1) -> gate (z2n from pass1) -> GEMM2 -> +x +b2 -> out
__global__ __launch_bounds__(256, 4)
void pass2_kernel(const float* __restrict__ x, const int* __restrict__ seg,
                  const __bf16* __restrict__ w1p, const float* __restrict__ b1,
                  const __bf16* __restrict__ w2p, const float* __restrict__ b2,
                  const float* __restrict__ n1w, const float* __restrict__ n1b,
                  const float* __restrict__ alpha_p, const float* __restrict__ G,
                  const __bf16* __restrict__ z2n, float* __restrict__ out) {
    __shared__ __align__(16) __bf16 ys[32 * 128];   // XOR-swz
    __shared__ __align__(16) __bf16 zs[32 * 256];   // XOR-swz: idx = r*256 + (col ^ ((r&7)<<3))

    const int tid = threadIdx.x;
    const int lane = tid & 63;
    const int wv = tid >> 6;
    const int q = lane >> 4, m0 = lane & 15;
    const size_t row0 = (size_t)blockIdx.x * 32;
    const int r = tid >> 3, g = tid & 7;

    // 2-deep b-frag ring (wave wv owns z1 tiles nt_g = wv*4 .. +3)
    short8 bb[2][4];
    #pragma unroll
    for (int p = 0; p < 2; ++p)
        #pragma unroll
        for (int kt = 0; kt < 4; ++kt)
            bb[p][kt] = *reinterpret_cast<const short8*>(
                w1p + ((size_t)((wv * 4 + p) * 4 + kt) * 64 + lane) * 8);
    float b1v[4];
    #pragma unroll
    for (int nt = 0; nt < 4; ++nt) b1v[nt] = b1[(wv * 4 + nt) * 16 + m0];

    const int segi = seg[row0 + r];
    const float alpha = alpha_p[0];

    float xr[16];
    #pragma unroll
    for (int i = 0; i < 4; ++i) {
        float4 t = *reinterpret_cast<const float4*>(x + (row0 + r) * D + g * 16 + i * 4);
        xr[i * 4 + 0] = t.x; xr[i * 4 + 1] = t.y; xr[i * 4 + 2] = t.z; xr[i * 4 + 3] = t.w;
    }
    float w1r[16], c1r[16];
    #pragma unroll
    for (int i = 0; i < 4; ++i) {
        float4 t = *reinterpret_cast<const float4*>(n1w + g * 16 + i * 4);
        w1r[i * 4 + 0] = t.x; w1r[i * 4 + 1] = t.y; w1r[i * 4 + 2] = t.z; w1r[i * 4 + 3] = t.w;
        float4 u = *reinterpret_cast<const float4*>(n1b + g * 16 + i * 4);
        c1r[i * 4 + 0] = u.x; c1r[i * 4 + 1] = u.y; c1r[i * 4 + 2] = u.z; c1r[i * 4 + 3] = u.w;
    }

    { // LN1 fully in registers
        float s = 0.f, ss = 0.f;
        #pragma unroll
        for (int i = 0; i < 16; ++i) { s += xr[i]; ss += xr[i] * xr[i]; }
        s += __shfl_xor(s, 1); ss += __shfl_xor(ss, 1);
        s += __shfl_xor(s, 2); ss += __shfl_xor(ss, 2);
        s += __shfl_xor(s, 4); ss += __shfl_xor(ss, 4);
        float mean = s * (1.f / 128.f);
        float var = ss * (1.f / 128.f) - mean * mean;
        float rsv = rsqrtf(var + EPS);
        const int swr = (r & 7) << 3;
        #pragma unroll
        for (int h = 0; h < 2; ++h) {
            short8 pk;
            #pragma unroll
            for (int j = 0; j < 8; ++j)
                pk[j] = f2bf((xr[h * 8 + j] - mean) * rsv * w1r[h * 8 + j] + c1r[h * 8 + j]);
            *reinterpret_cast<short8*>(&ys[r * 128 + ((g * 16 + h * 8) ^ swr)]) = pk;
        }
    }
    __syncthreads();

    { // half GEMM1 (z1 cols 0..255)
        const int swm = (m0 & 7) << 3;
        const int ccol = q << 3;
        short8 a0[4], a1[4];
        #pragma unroll
        for (int kt = 0; kt < 4; ++kt) {
            a0[kt] = *reinterpret_cast<const short8*>(&ys[m0 * 128 + ((kt * 32 + ccol) ^ swm)]);
            a1[kt] = *reinterpret_cast<const short8*>(&ys[(m0 + 16) * 128 + ((kt * 32 + ccol) ^ swm)]);
        }
        #pragma unroll
        for (int nt = 0; nt < 4; ++nt) {
            f32x4 acc0 = {0.f, 0.f, 0.f, 0.f};
            f32x4 acc1 = {0.f, 0.f, 0.f, 0.f};
            #pragma unroll
            for (int kt = 0; kt < 4; ++kt) {
                acc0 = __builtin_amdgcn_mfma_f32_16x16x32_bf16(a0[kt], bb[nt & 1][kt], acc0, 0, 0, 0);
                acc1 = __builtin_amdgcn_mfma_f32_16x16x32_bf16(a1[kt], bb[nt & 1][kt], acc1, 0, 0, 0);
            }
            if (nt < 2) {
                #pragma unroll
                for (int kt = 0; kt < 4; ++kt)
                    bb[nt & 1][kt] = *reinterpret_cast<const short8*>(
                        w1p + ((size_t)((wv * 4 + nt + 2) * 4 + kt) * 64 + lane) * 8);
            }
            int cz = (wv * 4 + nt) * 16 + m0;
            #pragma unroll
            for (int reg = 0; reg < 4; ++reg) {
                int r0 = (q << 2) + reg;
                int r1 = r0 + 16;
                zs[r0 * 256 + (cz ^ ((r0 & 7) << 3))] = (__bf16)selu_f(acc0[reg] + b1v[nt]);
                zs[r1 * 256 + (cz ^ ((r1 & 7) << 3))] = (__bf16)selu_f(acc1[reg] + b1v[nt]);
            }
        }
    }

    // Issue gate inputs + GEMM2 weight frags NOW — latency hides under barrier + gate phase.
    short8 zn[4];
    #pragma unroll
    for (int i = 0; i < 4; ++i)
        zn[i] = *reinterpret_cast<const short8*>(z2n + (row0 + r) * H + g * 32 + i * 8);
    float gvf[32];
    {
        const float* Gp = G + (size_t)segi * H + g * 32;
        #pragma unroll
        for (int i = 0; i < 8; ++i) {
            float4 t = *reinterpret_cast<const float4*>(Gp + i * 4);
            gvf[i * 4 + 0] = t.x; gvf[i * 4 + 1] = t.y; gvf[i * 4 + 2] = t.z; gvf[i * 4 + 3] = t.w;
        }
    }
    short8 b2f[2][8];
    #pragma unroll
    for (int p = 0; p < 2; ++p)
        #pragma unroll
        for (int kt = 0; kt < 8; ++kt)
            b2f[p][kt] = *reinterpret_cast<const short8*>(
                w2p + ((size_t)((wv * 2 + p) * 8 + kt) * 64 + lane) * 8);
    float b2v[2];
    #pragma unroll
    for (int p = 0; p < 2; ++p) b2v[p] = b2[(wv * 2 + p) * 16 + m0];
    __syncthreads();

    { // gate: A2 = z1 * (z2n*alpha + 1 + G), fully short8-vectorized
        const int swr = (r & 7) << 3;
        #pragma unroll
        for (int i = 0; i < 4; ++i) {
            int idx = r * 256 + ((g * 32 + i * 8) ^ swr);
            short8 v = *reinterpret_cast<const short8*>(&zs[idx]);
            short8 o;
            #pragma unroll
            for (int j = 0; j < 8; ++j) {
                float gate = bf2f(zn[i][j]) * alpha + 1.f + gvf[i * 8 + j];
                o[j] = f2bf(bf2f(v[j]) * gate);
            }
            *reinterpret_cast<short8*>(&zs[idx]) = o;
        }
    }
    // residual reads (consumed in GEMM2 epilogue; latency hides under GEMM2)
    float xres[16];
    #pragma unroll
    for (int p = 0; p < 2; ++p) {
        int col = (wv * 2 + p) * 16 + m0;
        #pragma unroll
        for (int reg = 0; reg < 4; ++reg) {
            int r0 = (q << 2) + reg;
            xres[p * 8 + reg]     = x[(row0 + r0) * D + col];
            xres[p * 8 + 4 + reg] = x[(row0 + r0 + 16) * D + col];
        }
    }
    __syncthreads();

    { // GEMM2: (32x256)@(256x128), direct store out = acc + b2 + x
        const int swm = (m0 & 7) << 3;
        const int ccol = q << 3;
        f32x4 zero = {0.f, 0.f, 0.f, 0.f};
        f32x4 acc[2][2] = {{zero, zero}, {zero, zero}};
        #pragma unroll
        for (int kt = 0; kt < 8; ++kt) {
            short8 a0 = *reinterpret_cast<const short8*>(&zs[m0 * 256 + ((kt * 32 + ccol) ^ swm)]);
            short8 a1 = *reinterpret_cast<const short8*>(&zs[(m0 + 16) * 256 + ((kt * 32 + ccol) ^ swm)]);
            #pragma unroll
            for (int p = 0; p < 2; ++p) {
                acc[p][0] = __builtin_amdgcn_mfma_f32_16x16x32_bf16(a0, b2f[p][kt], acc[p][0], 0, 0, 0);
                acc[p][1] = __builtin_amdgcn_mfma_f32_16x16x32_bf16(a1, b2f[p][kt], acc[p][1], 0, 0, 0);
            }
        }
        #pragma unroll
        for (int p = 0; p < 2; ++p) {
            int col = (wv * 2 + p) * 16 + m0;
            #pragma unroll
            for (int reg = 0; reg < 4; ++reg) {
                int r0 = (q << 2) + reg;
                out[(row0 + r0) * D + col]      = acc[p][0][reg] + b2v[p] + xres[p * 8 + reg];
                out[(row0 + r0 + 16) * D + col] = acc[p][1][reg] + b2v[p] + xres[p * 8 + 4 + reg];
            }
        }
    }
}

extern "C" void kernel_launch(void* const* d_in, const int* in_sizes, int n_in,
                              void* d_out, int out_size, void* d_ws, size_t ws_size,
                              hipStream_t stream) {
    const float* ref_flat = (const float*)d_in[0];
    const float* alt_flat = (const float*)d_in[1];
    const int*   ref_seg  = (const int*)d_in[2];
    const int*   alt_seg  = (const int*)d_in[3];
    const float* norm1_w  = (const float*)d_in[4];
    const float* norm1_b  = (const float*)d_in[5];
    const float* w1_ref   = (const float*)d_in[6];
    const float* b1_ref   = (const float*)d_in[7];
    const float* w1_alt   = (const float*)d_in[8];
    const float* b1_alt   = (const float*)d_in[9];
    const float* norm2_w  = (const float*)d_in[10];
    const float* norm2_b  = (const float*)d_in[11];
    const float* alpha_ref = (const float*)d_in[12];
    const float* alpha_alt = (const float*)d_in[13];
    const float* beta_ref  = (const float*)d_in[14];
    const float* beta_alt  = (const float*)d_in[15];
    const float* gamma     = (const float*)d_in[16];
    const float* ref_regularizer = (const float*)d_in[17];
    const float* reg_w_pre = (const float*)d_in[18];
    const float* w2_ref   = (const float*)d_in[19];
    const float* b2_ref   = (const float*)d_in[20];
    const float* w2_alt   = (const float*)d_in[21];
    const float* b2_alt   = (const float*)d_in[22];

    char* ws = (char*)d_ws;
    float* sum_r = (float*)(ws);                      // 4 MB
    float* sum_a = (float*)(ws + 4194304);            // 4 MB
    float* cnt_r = (float*)(ws + 8388608);            // 16 KB
    float* cnt_a = (float*)(ws + 8404992);            // 16 KB
    float* G_ref = (float*)(ws + 8421376);            // 4 MB
    float* G_alt = (float*)(ws + 12615680);           // 4 MB
    __bf16* w1p_r = (__bf16*)(ws + 16809984);         // 128 KB
    __bf16* w1p_a = (__bf16*)(ws + 16941056);         // 128 KB
    __bf16* w2p_r = (__bf16*)(ws + 17072128);         // 64 KB
    __bf16* w2p_a = (__bf16*)(ws + 17137664);         // 64 KB
    __bf16* z2nb  = (__bf16*)(ws + 17203200);         // 64 MB (ref then reused for alt)

    hipMemsetAsync(d_ws, 0, 8421376, stream);  // zero sums + counts (atomic targets)

    pack_w<<<256, 256, 0, stream>>>(w1_ref, w1p_r, 4, F);
    pack_w<<<256, 256, 0, stream>>>(w1_alt, w1p_a, 4, F);
    pack_w<<<128, 256, 0, stream>>>(w2_ref, w2p_r, 8, D);
    pack_w<<<128, 256, 0, stream>>>(w2_alt, w2p_a, 8, D);

    // ref chain
    pass1_kernel<<<NREF/32, 256, 0, stream>>>(ref_flat, ref_seg, w1p_r, b1_ref,
                                              norm1_w, norm1_b, norm2_w, norm2_b,
                                              sum_r, cnt_r, z2nb);
    mf_ref_kernel<<<BSEG, 256, 0, stream>>>(sum_r, cnt_r, ref_regularizer, reg_w_pre,
                                            beta_ref, G_ref);
    pass2_kernel<<<NREF/32, 256, 0, stream>>>(ref_flat, ref_seg, w1p_r, b1_ref, w2p_r, b2_ref,
                                              norm1_w, norm1_b, alpha_ref, G_ref, z2nb,
                                              (float*)d_out);

    // alt chain (z2n buffer reused — pass2_ref has completed in stream order)
    pass1_kernel<<<NALT/32, 256, 0, stream>>>(alt_flat, alt_seg, w1p_a, b1_alt,
                                              norm1_w, norm1_b, norm2_w, norm2_b,
                                              sum_a, cnt_a, z2nb);
    mf_alt_kernel<<<BSEG, 256, 0, stream>>>(sum_r, cnt_r, sum_a, cnt_a,
                                            ref_regularizer, reg_w_pre,
                                            beta_alt, gamma, G_alt);
    pass2_kernel<<<NALT/32, 256, 0, stream>>>(alt_flat, alt_seg, w1p_a, b1_alt, w2p_a, b2_alt,
                                              norm1_w, norm1_b, alpha_alt, G_alt, z2nb,
                                              (float*)d_out + (size_t)NREF * D);
}

// Round 5
// 300.322 us; speedup vs baseline: 1.5850x; 1.0800x over previous
//
#include <hip/hip_runtime.h>
#include <hip/hip_bf16.h>

#define NREF 131072
#define NALT 32768
#define BSEG 4096
#define D 128
#define F 512
#define H 256
#define EPS 1e-5f
#define NB_REF 4096
#define NB_ALT 1024

typedef short short8 __attribute__((ext_vector_type(8)));
typedef float f32x4 __attribute__((ext_vector_type(4)));

__device__ __forceinline__ float selu_f(float z) {
    const float sc = 1.0507009873554805f;
    const float al = 1.6732632423543772f;
    return z > 0.f ? sc * z : sc * al * (__expf(z) - 1.f);
}

__device__ __forceinline__ short f2bf(float v) {
    __bf16 b = (__bf16)v;
    return __builtin_bit_cast(short, b);
}

__device__ __forceinline__ float bf2f(short s) {
    return (float)__builtin_bit_cast(__bf16, s);
}

// Fused: pack 4 weight matrices into MFMA B-fragment layout + zero atomic buffers.
// Pack mapping: frag ((nt*KT+kt)*64+lane)*8+j <-> W[kt*32+(lane>>4)*8+j][nt*16+(lane&15)]
__global__ void prep_kernel(const float* __restrict__ w1_ref, const float* __restrict__ w1_alt,
                            const float* __restrict__ w2_ref, const float* __restrict__ w2_alt,
                            __bf16* __restrict__ w1p_r, __bf16* __restrict__ w1p_a,
                            __bf16* __restrict__ w2p_r, __bf16* __restrict__ w2p_a,
                            float* __restrict__ zbase) {
    int b = blockIdx.x;
    if (b < 768) {
        const float* w; __bf16* wp; int KT, N, idx;
        if (b < 256)      { w = w1_ref; wp = w1p_r; KT = 4; N = F; idx = b * 256 + threadIdx.x; }
        else if (b < 512) { w = w1_alt; wp = w1p_a; KT = 4; N = F; idx = (b - 256) * 256 + threadIdx.x; }
        else if (b < 640) { w = w2_ref; wp = w2p_r; KT = 8; N = D; idx = (b - 512) * 256 + threadIdx.x; }
        else              { w = w2_alt; wp = w2p_a; KT = 8; N = D; idx = (b - 640) * 256 + threadIdx.x; }
        int j = idx & 7;
        int l = (idx >> 3) & 63;
        int t = idx >> 9;
        int kt = t % KT;
        int nt = t / KT;
        int k = kt * 32 + ((l >> 4) << 3) + j;
        int n = (nt << 4) + (l & 15);
        wp[idx] = (__bf16)w[k * N + n];
    } else {
        // zero 8421376 bytes (sum_r, sum_a, cnt_r, cnt_a) = 526336 float4
        int t = (b - 768) * 256 + threadIdx.x;   // 0..131071
        float4 z = {0.f, 0.f, 0.f, 0.f};
        for (int i = t; i < 526336; i += 512 * 256)
            reinterpret_cast<float4*>(zbase)[i] = z;
    }
}

// Pass 1 (ref+alt merged): LN1 -> half GEMM1 (z2 cols) -> SELU -> LN2 -> seg sums + z2n store
__global__ __launch_bounds__(256, 4)
void pass1_kernel(const float* __restrict__ xr_, const float* __restrict__ xa_,
                  const int* __restrict__ segr_, const int* __restrict__ sega_,
                  const __bf16* __restrict__ w1pr_, const __bf16* __restrict__ w1pa_,
                  const float* __restrict__ b1r_, const float* __restrict__ b1a_,
                  const float* __restrict__ n1w, const float* __restrict__ n1b,
                  const float* __restrict__ n2w, const float* __restrict__ n2b,
                  float* __restrict__ sumr_, float* __restrict__ cntr_,
                  float* __restrict__ suma_, float* __restrict__ cnta_,
                  __bf16* __restrict__ z2nr_, __bf16* __restrict__ z2na_,
                  int boff) {
    __shared__ __align__(16) __bf16 ys[32 * 128];    // XOR-swz: idx = r*128 + (col ^ ((r&7)<<3))
    __shared__ __align__(16) __bf16 z2s[32 * 256];   // XOR-swz: idx = r*256 + (col ^ ((r&7)<<3))
    __shared__ float n2w_s[H], n2b_s[H];
    __shared__ int seg_s[32];

    const int b = blockIdx.x + boff;
    const float* x; const int* seg; const __bf16* w1p; const float* b1;
    float* seg_sum; float* seg_cnt; __bf16* z2n_out; size_t row0;
    if (b < NB_REF) {
        x = xr_; seg = segr_; w1p = w1pr_; b1 = b1r_;
        seg_sum = sumr_; seg_cnt = cntr_; z2n_out = z2nr_;
        row0 = (size_t)b * 32;
    } else {
        x = xa_; seg = sega_; w1p = w1pa_; b1 = b1a_;
        seg_sum = suma_; seg_cnt = cnta_; z2n_out = z2na_;
        row0 = (size_t)(b - NB_REF) * 32;
    }

    const int tid = threadIdx.x;
    const int lane = tid & 63;
    const int wv = tid >> 6;
    const int q = lane >> 4, m0 = lane & 15;

    // 2-deep b-frag ring (wave wv owns nt_g = 16+wv*4 .. +3)
    short8 bb[2][4];
    #pragma unroll
    for (int p = 0; p < 2; ++p)
        #pragma unroll
        for (int kt = 0; kt < 4; ++kt)
            bb[p][kt] = *reinterpret_cast<const short8*>(
                w1p + ((size_t)((16 + wv * 4 + p) * 4 + kt) * 64 + lane) * 8);
    float b1v[4];
    #pragma unroll
    for (int nt = 0; nt < 4; ++nt) b1v[nt] = b1[256 + (wv * 4 + nt) * 16 + m0];

    const int r = tid >> 3, g = tid & 7;
    float xr[16];
    #pragma unroll
    for (int i = 0; i < 4; ++i) {
        float4 t = *reinterpret_cast<const float4*>(x + (row0 + r) * D + g * 16 + i * 4);
        xr[i * 4 + 0] = t.x; xr[i * 4 + 1] = t.y; xr[i * 4 + 2] = t.z; xr[i * 4 + 3] = t.w;
    }
    float w1r[16], c1r[16];   // LN1 weights in regs (no LDS -> no pre-barrier race)
    #pragma unroll
    for (int i = 0; i < 4; ++i) {
        float4 t = *reinterpret_cast<const float4*>(n1w + g * 16 + i * 4);
        w1r[i * 4 + 0] = t.x; w1r[i * 4 + 1] = t.y; w1r[i * 4 + 2] = t.z; w1r[i * 4 + 3] = t.w;
        float4 u = *reinterpret_cast<const float4*>(n1b + g * 16 + i * 4);
        c1r[i * 4 + 0] = u.x; c1r[i * 4 + 1] = u.y; c1r[i * 4 + 2] = u.z; c1r[i * 4 + 3] = u.w;
    }

    n2w_s[tid] = n2w[tid]; n2b_s[tid] = n2b[tid];
    if (tid < 32) seg_s[tid] = seg[row0 + tid];

    { // LN1 fully in registers (8 threads/row)
        float s = 0.f, ss = 0.f;
        #pragma unroll
        for (int i = 0; i < 16; ++i) { s += xr[i]; ss += xr[i] * xr[i]; }
        s += __shfl_xor(s, 1); ss += __shfl_xor(ss, 1);
        s += __shfl_xor(s, 2); ss += __shfl_xor(ss, 2);
        s += __shfl_xor(s, 4); ss += __shfl_xor(ss, 4);
        float mean = s * (1.f / 128.f);
        float var = ss * (1.f / 128.f) - mean * mean;
        float rsv = rsqrtf(var + EPS);
        const int swr = (r & 7) << 3;
        #pragma unroll
        for (int h = 0; h < 2; ++h) {
            short8 pk;
            #pragma unroll
            for (int j = 0; j < 8; ++j)
                pk[j] = f2bf((xr[h * 8 + j] - mean) * rsv * w1r[h * 8 + j] + c1r[h * 8 + j]);
            *reinterpret_cast<short8*>(&ys[r * 128 + ((g * 16 + h * 8) ^ swr)]) = pk;
        }
    }
    __syncthreads();

    { // half GEMM1 (z2 cols), wave wv: 4 nt x 2 mt x 4 kt
        const int swm = (m0 & 7) << 3;
        const int ccol = q << 3;
        short8 a0[4], a1[4];
        #pragma unroll
        for (int kt = 0; kt < 4; ++kt) {
            a0[kt] = *reinterpret_cast<const short8*>(&ys[m0 * 128 + ((kt * 32 + ccol) ^ swm)]);
            a1[kt] = *reinterpret_cast<const short8*>(&ys[(m0 + 16) * 128 + ((kt * 32 + ccol) ^ swm)]);
        }
        #pragma unroll
        for (int nt = 0; nt < 4; ++nt) {
            f32x4 acc0 = {0.f, 0.f, 0.f, 0.f};
            f32x4 acc1 = {0.f, 0.f, 0.f, 0.f};
            #pragma unroll
            for (int kt = 0; kt < 4; ++kt) {
                acc0 = __builtin_amdgcn_mfma_f32_16x16x32_bf16(a0[kt], bb[nt & 1][kt], acc0, 0, 0, 0);
                acc1 = __builtin_amdgcn_mfma_f32_16x16x32_bf16(a1[kt], bb[nt & 1][kt], acc1, 0, 0, 0);
            }
            if (nt < 2) {
                #pragma unroll
                for (int kt = 0; kt < 4; ++kt)
                    bb[nt & 1][kt] = *reinterpret_cast<const short8*>(
                        w1p + ((size_t)((16 + wv * 4 + nt + 2) * 4 + kt) * 64 + lane) * 8);
            }
            int cz = (wv * 4 + nt) * 16 + m0;   // 0..255 within z2
            #pragma unroll
            for (int reg = 0; reg < 4; ++reg) {
                int r0 = (q << 2) + reg;
                int r1 = r0 + 16;
                z2s[r0 * 256 + (cz ^ ((r0 & 7) << 3))] = (__bf16)selu_f(acc0[reg] + b1v[nt]);
                z2s[r1 * 256 + (cz ^ ((r1 & 7) << 3))] = (__bf16)selu_f(acc1[reg] + b1v[nt]);
            }
        }
    }
    __syncthreads();

    { // LN2 (thread = row, vectorized short8) + bf16 z2n store to global
        const int swr = (r & 7) << 3;
        float vb[32];
        float s2 = 0.f, q2 = 0.f;
        #pragma unroll
        for (int i = 0; i < 4; ++i) {
            short8 v = *reinterpret_cast<const short8*>(&z2s[r * 256 + ((g * 32 + i * 8) ^ swr)]);
            #pragma unroll
            for (int j = 0; j < 8; ++j) {
                float f = bf2f(v[j]);
                vb[i * 8 + j] = f; s2 += f; q2 += f * f;
            }
        }
        s2 += __shfl_xor(s2, 1); q2 += __shfl_xor(q2, 1);
        s2 += __shfl_xor(s2, 2); q2 += __shfl_xor(q2, 2);
        s2 += __shfl_xor(s2, 4); q2 += __shfl_xor(q2, 4);
        float mean2 = s2 * (1.f / 256.f);
        float var2 = q2 * (1.f / 256.f) - mean2 * mean2;
        float rs2 = rsqrtf(var2 + EPS);
        #pragma unroll
        for (int i = 0; i < 4; ++i) {
            short8 o;
            #pragma unroll
            for (int j = 0; j < 8; ++j) {
                int col = g * 32 + i * 8 + j;
                o[j] = f2bf((vb[i * 8 + j] - mean2) * rs2 * n2w_s[col] + n2b_s[col]);
            }
            *reinterpret_cast<short8*>(&z2s[r * 256 + ((g * 32 + i * 8) ^ swr)]) = o;
            *reinterpret_cast<short8*>(z2n_out + (row0 + r) * H + g * 32 + i * 8) = o;
        }
    }
    __syncthreads();

    { // segment accumulate: thread = column, run-length compress (segments sorted)
        int c = tid;
        int s_cur = seg_s[0];
        float run = 0.f;
        for (int rr = 0; rr < 32; ++rr) {
            int sg = seg_s[rr];
            if (sg != s_cur) {
                atomicAdd(&seg_sum[(size_t)s_cur * H + c], run);
                run = 0.f; s_cur = sg;
            }
            run += (float)z2s[rr * 256 + (c ^ ((rr & 7) << 3))];
        }
        atomicAdd(&seg_sum[(size_t)s_cur * H + c], run);
        if (tid == 0) {
            int sc = seg_s[0]; float rl = 0.f;
            for (int rr = 0; rr < 32; ++rr) {
                if (seg_s[rr] != sc) { atomicAdd(&seg_cnt[sc], rl); rl = 0.f; sc = seg_s[rr]; }
                rl += 1.f;
            }
            atomicAdd(&seg_cnt[sc], rl);
        }
    }
}

// Combined: G_ref = beta_ref*mf_ref ; G_alt = beta_alt*mf_alt + gamma*mf_ref
__global__ void mf_kernel(const float* __restrict__ sum_r, const float* __restrict__ cnt_r,
                          const float* __restrict__ sum_a, const float* __restrict__ cnt_a,
                          const float* __restrict__ regz, const float* __restrict__ reg_w_pre,
                          const float* __restrict__ beta_ref, const float* __restrict__ beta_alt,
                          const float* __restrict__ gamma,
                          float* __restrict__ G_ref, float* __restrict__ G_alt) {
    int s = blockIdx.x, c = threadIdx.x;
    size_t i = (size_t)s * H + c;
    float rw = __expf(reg_w_pre[0]) + 0.25f;
    float mfr = (sum_r[i] + rw * regz[c]) / (cnt_r[s] + rw);
    float mfa = sum_a[i] / fmaxf(cnt_a[s], 1.f);
    G_ref[i] = beta_ref[0] * mfr;
    G_alt[i] = beta_alt[0] * mfa + gamma[0] * mfr;
}

// Pass 2 (ref+alt merged): LN1 -> half GEMM1 (z1) -> gate (z2n) -> GEMM2 -> +x +b2 -> out
__global__ __launch_bounds__(256, 4)
void pass2_kernel(const float* __restrict__ xr_, const float* __restrict__ xa_,
                  const int* __restrict__ segr_, const int* __restrict__ sega_,
                  const __bf16* __restrict__ w1pr_, const __bf16* __restrict__ w1pa_,
                  const float* __restrict__ b1r_, const float* __restrict__ b1a_,
                  const __bf16* __restrict__ w2pr_, const __bf16* __restrict__ w2pa_,
                  const float* __restrict__ b2r_, const float* __restrict__ b2a_,
                  const float* __restrict__ n1w, const float* __restrict__ n1b,
                  const float* __restrict__ alphar_, const float* __restrict__ alphaa_,
                  const float* __restrict__ Gr_, const float* __restrict__ Ga_,
                  const __bf16* __restrict__ z2nr_, const __bf16* __restrict__ z2na_,
                  float* __restrict__ out_, int boff) {
    __shared__ __align__(16) __bf16 ys[32 * 128];   // XOR-swz
    __shared__ __align__(16) __bf16 zs[32 * 256];   // XOR-swz: idx = r*256 + (col ^ ((r&7)<<3))

    const int b = blockIdx.x + boff;
    const float* x; const int* seg; const __bf16* w1p; const float* b1;
    const __bf16* w2p; const float* b2; const float* alpha_p; const float* G;
    const __bf16* z2n; float* out; size_t row0;
    if (b < NB_REF) {
        x = xr_; seg = segr_; w1p = w1pr_; b1 = b1r_; w2p = w2pr_; b2 = b2r_;
        alpha_p = alphar_; G = Gr_; z2n = z2nr_; out = out_;
        row0 = (size_t)b * 32;
    } else {
        x = xa_; seg = sega_; w1p = w1pa_; b1 = b1a_; w2p = w2pa_; b2 = b2a_;
        alpha_p = alphaa_; G = Ga_; z2n = z2na_; out = out_ + (size_t)NREF * D;
        row0 = (size_t)(b - NB_REF) * 32;
    }

    const int tid = threadIdx.x;
    const int lane = tid & 63;
    const int wv = tid >> 6;
    const int q = lane >> 4, m0 = lane & 15;
    const int r = tid >> 3, g = tid & 7;

    // 2-deep b-frag ring (wave wv owns z1 tiles nt_g = wv*4 .. +3)
    short8 bb[2][4];
    #pragma unroll
    for (int p = 0; p < 2; ++p)
        #pragma unroll
        for (int kt = 0; kt < 4; ++kt)
            bb[p][kt] = *reinterpret_cast<const short8*>(
                w1p + ((size_t)((wv * 4 + p) * 4 + kt) * 64 + lane) * 8);
    float b1v[4];
    #pragma unroll
    for (int nt = 0; nt < 4; ++nt) b1v[nt] = b1[(wv * 4 + nt) * 16 + m0];

    const int segi = seg[row0 + r];
    const float alpha = alpha_p[0];

    float xr[16];
    #pragma unroll
    for (int i = 0; i < 4; ++i) {
        float4 t = *reinterpret_cast<const float4*>(x + (row0 + r) * D + g * 16 + i * 4);
        xr[i * 4 + 0] = t.x; xr[i * 4 + 1] = t.y; xr[i * 4 + 2] = t.z; xr[i * 4 + 3] = t.w;
    }
    float w1r[16], c1r[16];
    #pragma unroll
    for (int i = 0; i < 4; ++i) {
        float4 t = *reinterpret_cast<const float4*>(n1w + g * 16 + i * 4);
        w1r[i * 4 + 0] = t.x; w1r[i * 4 + 1] = t.y; w1r[i * 4 + 2] = t.z; w1r[i * 4 + 3] = t.w;
        float4 u = *reinterpret_cast<const float4*>(n1b + g * 16 + i * 4);
        c1r[i * 4 + 0] = u.x; c1r[i * 4 + 1] = u.y; c1r[i * 4 + 2] = u.z; c1r[i * 4 + 3] = u.w;
    }

    { // LN1 fully in registers
        float s = 0.f, ss = 0.f;
        #pragma unroll
        for (int i = 0; i < 16; ++i) { s += xr[i]; ss += xr[i] * xr[i]; }
        s += __shfl_xor(s, 1); ss += __shfl_xor(ss, 1);
        s += __shfl_xor(s, 2); ss += __shfl_xor(ss, 2);
        s += __shfl_xor(s, 4); ss += __shfl_xor(ss, 4);
        float mean = s * (1.f / 128.f);
        float var = ss * (1.f / 128.f) - mean * mean;
        float rsv = rsqrtf(var + EPS);
        const int swr = (r & 7) << 3;
        #pragma unroll
        for (int h = 0; h < 2; ++h) {
            short8 pk;
            #pragma unroll
            for (int j = 0; j < 8; ++j)
                pk[j] = f2bf((xr[h * 8 + j] - mean) * rsv * w1r[h * 8 + j] + c1r[h * 8 + j]);
            *reinterpret_cast<short8*>(&ys[r * 128 + ((g * 16 + h * 8) ^ swr)]) = pk;
        }
    }
    __syncthreads();

    { // half GEMM1 (z1 cols 0..255)
        const int swm = (m0 & 7) << 3;
        const int ccol = q << 3;
        short8 a0[4], a1[4];
        #pragma unroll
        for (int kt = 0; kt < 4; ++kt) {
            a0[kt] = *reinterpret_cast<const short8*>(&ys[m0 * 128 + ((kt * 32 + ccol) ^ swm)]);
            a1[kt] = *reinterpret_cast<const short8*>(&ys[(m0 + 16) * 128 + ((kt * 32 + ccol) ^ swm)]);
        }
        #pragma unroll
        for (int nt = 0; nt < 4; ++nt) {
            f32x4 acc0 = {0.f, 0.f, 0.f, 0.f};
            f32x4 acc1 = {0.f, 0.f, 0.f, 0.f};
            #pragma unroll
            for (int kt = 0; kt < 4; ++kt) {
                acc0 = __builtin_amdgcn_mfma_f32_16x16x32_bf16(a0[kt], bb[nt & 1][kt], acc0, 0, 0, 0);
                acc1 = __builtin_amdgcn_mfma_f32_16x16x32_bf16(a1[kt], bb[nt & 1][kt], acc1, 0, 0, 0);
            }
            if (nt < 2) {
                #pragma unroll
                for (int kt = 0; kt < 4; ++kt)
                    bb[nt & 1][kt] = *reinterpret_cast<const short8*>(
                        w1p + ((size_t)((wv * 4 + nt + 2) * 4 + kt) * 64 + lane) * 8);
            }
            int cz = (wv * 4 + nt) * 16 + m0;
            #pragma unroll
            for (int reg = 0; reg < 4; ++reg) {
                int r0 = (q << 2) + reg;
                int r1 = r0 + 16;
                zs[r0 * 256 + (cz ^ ((r0 & 7) << 3))] = (__bf16)selu_f(acc0[reg] + b1v[nt]);
                zs[r1 * 256 + (cz ^ ((r1 & 7) << 3))] = (__bf16)selu_f(acc1[reg] + b1v[nt]);
            }
        }
    }

    // Issue gate inputs + GEMM2 weight frags NOW — latency hides under barrier + gate phase.
    short8 zn[4];
    #pragma unroll
    for (int i = 0; i < 4; ++i)
        zn[i] = *reinterpret_cast<const short8*>(z2n + (row0 + r) * H + g * 32 + i * 8);
    float gvf[32];
    {
        const float* Gp = G + (size_t)segi * H + g * 32;
        #pragma unroll
        for (int i = 0; i < 8; ++i) {
            float4 t = *reinterpret_cast<const float4*>(Gp + i * 4);
            gvf[i * 4 + 0] = t.x; gvf[i * 4 + 1] = t.y; gvf[i * 4 + 2] = t.z; gvf[i * 4 + 3] = t.w;
        }
    }
    short8 b2f[2][8];
    #pragma unroll
    for (int p = 0; p < 2; ++p)
        #pragma unroll
        for (int kt = 0; kt < 8; ++kt)
            b2f[p][kt] = *reinterpret_cast<const short8*>(
                w2p + ((size_t)((wv * 2 + p) * 8 + kt) * 64 + lane) * 8);
    float b2v[2];
    #pragma unroll
    for (int p = 0; p < 2; ++p) b2v[p] = b2[(wv * 2 + p) * 16 + m0];
    __syncthreads();

    { // gate: A2 = z1 * (z2n*alpha + 1 + G), fully short8-vectorized
        const int swr = (r & 7) << 3;
        #pragma unroll
        for (int i = 0; i < 4; ++i) {
            int idx = r * 256 + ((g * 32 + i * 8) ^ swr);
            short8 v = *reinterpret_cast<const short8*>(&zs[idx]);
            short8 o;
            #pragma unroll
            for (int j = 0; j < 8; ++j) {
                float gate = bf2f(zn[i][j]) * alpha + 1.f + gvf[i * 8 + j];
                o[j] = f2bf(bf2f(v[j]) * gate);
            }
            *reinterpret_cast<short8*>(&zs[idx]) = o;
        }
    }
    // residual reads (consumed in GEMM2 epilogue; latency hides under GEMM2)
    float xres[16];
    #pragma unroll
    for (int p = 0; p < 2; ++p) {
        int col = (wv * 2 + p) * 16 + m0;
        #pragma unroll
        for (int reg = 0; reg < 4; ++reg) {
            int r0 = (q << 2) + reg;
            xres[p * 8 + reg]     = x[(row0 + r0) * D + col];
            xres[p * 8 + 4 + reg] = x[(row0 + r0 + 16) * D + col];
        }
    }
    __syncthreads();

    { // GEMM2: (32x256)@(256x128), direct store out = acc + b2 + x
        const int swm = (m0 & 7) << 3;
        const int ccol = q << 3;
        f32x4 zero = {0.f, 0.f, 0.f, 0.f};
        f32x4 acc[2][2] = {{zero, zero}, {zero, zero}};
        #pragma unroll
        for (int kt = 0; kt < 8; ++kt) {
            short8 a0 = *reinterpret_cast<const short8*>(&zs[m0 * 256 + ((kt * 32 + ccol) ^ swm)]);
            short8 a1 = *reinterpret_cast<const short8*>(&zs[(m0 + 16) * 256 + ((kt * 32 + ccol) ^ swm)]);
            #pragma unroll
            for (int p = 0; p < 2; ++p) {
                acc[p][0] = __builtin_amdgcn_mfma_f32_16x16x32_bf16(a0, b2f[p][kt], acc[p][0], 0, 0, 0);
                acc[p][1] = __builtin_amdgcn_mfma_f32_16x16x32_bf16(a1, b2f[p][kt], acc[p][1], 0, 0, 0);
            }
        }
        #pragma unroll
        for (int p = 0; p < 2; ++p) {
            int col = (wv * 2 + p) * 16 + m0;
            #pragma unroll
            for (int reg = 0; reg < 4; ++reg) {
                int r0 = (q << 2) + reg;
                out[(row0 + r0) * D + col]      = acc[p][0][reg] + b2v[p] + xres[p * 8 + reg];
                out[(row0 + r0 + 16) * D + col] = acc[p][1][reg] + b2v[p] + xres[p * 8 + 4 + reg];
            }
        }
    }
}

extern "C" void kernel_launch(void* const* d_in, const int* in_sizes, int n_in,
                              void* d_out, int out_size, void* d_ws, size_t ws_size,
                              hipStream_t stream) {
    const float* ref_flat = (const float*)d_in[0];
    const float* alt_flat = (const float*)d_in[1];
    const int*   ref_seg  = (const int*)d_in[2];
    const int*   alt_seg  = (const int*)d_in[3];
    const float* norm1_w  = (const float*)d_in[4];
    const float* norm1_b  = (const float*)d_in[5];
    const float* w1_ref   = (const float*)d_in[6];
    const float* b1_ref   = (const float*)d_in[7];
    const float* w1_alt   = (const float*)d_in[8];
    const float* b1_alt   = (const float*)d_in[9];
    const float* norm2_w  = (const float*)d_in[10];
    const float* norm2_b  = (const float*)d_in[11];
    const float* alpha_ref = (const float*)d_in[12];
    const float* alpha_alt = (const float*)d_in[13];
    const float* beta_ref  = (const float*)d_in[14];
    const float* beta_alt  = (const float*)d_in[15];
    const float* gamma     = (const float*)d_in[16];
    const float* ref_regularizer = (const float*)d_in[17];
    const float* reg_w_pre = (const float*)d_in[18];
    const float* w2_ref   = (const float*)d_in[19];
    const float* b2_ref   = (const float*)d_in[20];
    const float* w2_alt   = (const float*)d_in[21];
    const float* b2_alt   = (const float*)d_in[22];

    char* ws = (char*)d_ws;
    float* sum_r = (float*)(ws);                      // 4 MB
    float* sum_a = (float*)(ws + 4194304);            // 4 MB
    float* cnt_r = (float*)(ws + 8388608);            // 16 KB
    float* cnt_a = (float*)(ws + 8404992);            // 16 KB
    float* G_ref = (float*)(ws + 8421376);            // 4 MB
    float* G_alt = (float*)(ws + 12615680);           // 4 MB
    __bf16* w1p_r = (__bf16*)(ws + 16809984);         // 128 KB
    __bf16* w1p_a = (__bf16*)(ws + 16941056);         // 128 KB
    __bf16* w2p_r = (__bf16*)(ws + 17072128);         // 64 KB
    __bf16* w2p_a = (__bf16*)(ws + 17137664);         // 64 KB
    __bf16* z2n_r = (__bf16*)(ws + 17203200);         // 64 MB
    __bf16* z2n_a = (__bf16*)(ws + 84312064);         // 16 MB (merged mode only)

    const bool merged = ws_size >= (size_t)101089280;   // constant across calls — capture-safe
    if (!merged) z2n_a = z2n_r;                          // sequential mode aliases the buffer

    // prep: 4 weight packs + zero 8.4 MB of atomic targets, one launch
    prep_kernel<<<1280, 256, 0, stream>>>(w1_ref, w1_alt, w2_ref, w2_alt,
                                          w1p_r, w1p_a, w2p_r, w2p_a, (float*)ws);

    if (merged) {
        pass1_kernel<<<NB_REF + NB_ALT, 256, 0, stream>>>(
            ref_flat, alt_flat, ref_seg, alt_seg, w1p_r, w1p_a, b1_ref, b1_alt,
            norm1_w, norm1_b, norm2_w, norm2_b,
            sum_r, cnt_r, sum_a, cnt_a, z2n_r, z2n_a, 0);
        mf_kernel<<<BSEG, 256, 0, stream>>>(sum_r, cnt_r, sum_a, cnt_a,
                                            ref_regularizer, reg_w_pre,
                                            beta_ref, beta_alt, gamma, G_ref, G_alt);
        pass2_kernel<<<NB_REF + NB_ALT, 256, 0, stream>>>(
            ref_flat, alt_flat, ref_seg, alt_seg, w1p_r, w1p_a, b1_ref, b1_alt,
            w2p_r, w2p_a, b2_ref, b2_alt, norm1_w, norm1_b,
            alpha_ref, alpha_alt, G_ref, G_alt, z2n_r, z2n_a, (float*)d_out, 0);
    } else {
        // sequential fallback (small workspace): ref chain then alt chain, z2n aliased
        pass1_kernel<<<NB_REF, 256, 0, stream>>>(
            ref_flat, alt_flat, ref_seg, alt_seg, w1p_r, w1p_a, b1_ref, b1_alt,
            norm1_w, norm1_b, norm2_w, norm2_b,
            sum_r, cnt_r, sum_a, cnt_a, z2n_r, z2n_a, 0);
        mf_kernel<<<BSEG, 256, 0, stream>>>(sum_r, cnt_r, sum_a, cnt_a,
                                            ref_regularizer, reg_w_pre,
                                            beta_ref, beta_alt, gamma, G_ref, G_alt);
        pass2_kernel<<<NB_REF, 256, 0, stream>>>(
            ref_flat, alt_flat, ref_seg, alt_seg, w1p_r, w1p_a, b1_ref, b1_alt,
            w2p_r, w2p_a, b2_ref, b2_alt, norm1_w, norm1_b,
            alpha_ref, alpha_alt, G_ref, G_alt, z2n_r, z2n_a, (float*)d_out, 0);
        pass1_kernel<<<NB_ALT, 256, 0, stream>>>(
            ref_flat, alt_flat, ref_seg, alt_seg, w1p_r, w1p_a, b1_ref, b1_alt,
            norm1_w, norm1_b, norm2_w, norm2_b,
            sum_r, cnt_r, sum_a, cnt_a, z2n_r, z2n_a, NB_REF);
        mf_kernel<<<BSEG, 256, 0, stream>>>(sum_r, cnt_r, sum_a, cnt_a,
                                            ref_regularizer, reg_w_pre,
                                            beta_ref, beta_alt, gamma, G_ref, G_alt);
        pass2_kernel<<<NB_ALT, 256, 0, stream>>>(
            ref_flat, alt_flat, ref_seg, alt_seg, w1p_r, w1p_a, b1_ref, b1_alt,
            w2p_r, w2p_a, b2_ref, b2_alt, norm1_w, norm1_b,
            alpha_ref, alpha_alt, G_ref, G_alt, z2n_r, z2n_a, (float*)d_out, NB_REF);
    }
}